// Round 8
// baseline (759.478 us; speedup 1.0000x reference)
//
#include <hip/hip_runtime.h>
#include <hip/hip_cooperative_groups.h>
#include <math.h>

namespace cg = cooperative_groups;

typedef unsigned short u16;
typedef unsigned int u32;
typedef __attribute__((ext_vector_type(8))) _Float16 half8;
typedef __attribute__((ext_vector_type(4))) float f32x4;

#define BL 8192          // B*L
#define DD 512           // d_model
#define NN 16            // state size
#define NCHUNK 64        // chunks per sequence
#define SCH 32           // chunk length (NCHUNK*SCH = L = 2048)
#define ZLD 640          // padded width of Z = [Bm(16)|Cm(16)|dt(512)|pad(96)]

__device__ __forceinline__ float softplus_f(float z) {
  float w = __builtin_amdgcn_exp2f(-1.4426950408889634f * fabsf(z));
  return fmaxf(z, 0.0f) + 0.69314718055994531f * __builtin_amdgcn_logf(1.0f + w);
}

__device__ __forceinline__ float gelu_erf(float y) {
  // exact-erf gelu via Abramowitz-Stegun 7.1.26 (max err ~1.5e-7)
  float ax = fabsf(y) * 0.70710678118654752f;
  float t  = __builtin_amdgcn_rcpf(1.0f + 0.3275911f * ax);
  float e  = __builtin_amdgcn_exp2f(-1.4426950408889634f * ax * ax);
  float p  = ((((1.061405429f * t - 1.453152027f) * t + 1.421413741f) * t
               - 0.284496736f) * t + 0.254829592f) * t;
  float er = copysignf(1.0f - p * e, y);
  return 0.5f * y * (1.0f + er);
}

// ---------------------------------------------------------------------------
// prep: fp16 copies of x and (transposed) weights, bias concat, A2
// ---------------------------------------------------------------------------
#define PREP_TOT (4194304 + 655360 + 524288 + 262144 + 1280 + 16384)
__global__ __launch_bounds__(256) void prep_kernel(
    const float* __restrict__ x, const float* __restrict__ A_log,
    const float* __restrict__ W_B, const float* __restrict__ b_B,
    const float* __restrict__ W_C, const float* __restrict__ b_C,
    const float* __restrict__ W_dt, const float* __restrict__ b_dt,
    const float* __restrict__ W_mix, const float* __restrict__ W_dec,
    _Float16* __restrict__ x16, _Float16* __restrict__ Wc16,
    _Float16* __restrict__ Wm16, _Float16* __restrict__ Wd16,
    float* __restrict__ bcat, float* __restrict__ A2)
{
  int i = blockIdx.x * 256 + threadIdx.x;
  if (i >= PREP_TOT) return;
  if (i < 4194304) { x16[i] = (_Float16)x[i]; return; }
  i -= 4194304;
  if (i < 655360) {                       // WcatT[l][n(640)][k(512)]
    int l = i / 327680, r = i % 327680, n = r >> 9, k = r & 511;
    float v = 0.0f;
    if (n < 16)       v = W_B[l * 8192 + k * 16 + n];
    else if (n < 32)  v = W_C[l * 8192 + k * 16 + (n - 16)];
    else if (n < 544) v = W_dt[l * 262144 + k * 512 + (n - 32)];
    Wc16[i] = (_Float16)v;
    return;
  }
  i -= 655360;
  if (i < 524288) {                       // WmixT[l][n][k]
    int l = i / 262144, r = i % 262144, n = r >> 9, k = r & 511;
    Wm16[i] = (_Float16)W_mix[l * 262144 + k * 512 + n];
    return;
  }
  i -= 524288;
  if (i < 262144) {                       // WdecT[n][k]
    int n = i >> 9, k = i & 511;
    Wd16[i] = (_Float16)W_dec[k * 512 + n];
    return;
  }
  i -= 262144;
  if (i < 1280) {                         // bcat[l][640]
    int l = i / 640, n = i % 640;
    float v = 0.0f;
    if (n < 16)       v = b_B[l * 16 + n];
    else if (n < 32)  v = b_C[l * 16 + (n - 16)];
    else if (n < 544) v = b_dt[l * 512 + (n - 32)];
    bcat[i] = v;
    return;
  }
  i -= 1280;
  // A2[l][d][n] = -exp(A_log)*log2(e)  (so a = exp2(dt*A2))
  A2[i] = -expf(A_log[i]) * 1.4426950408889634f;
}

// ---------------------------------------------------------------------------
// fp16 MFMA GEMM: C = A * Bt^T + bias. tile 128(M) x 64(N), BK=64 (8
// barriers instead of 16), 256 threads = 4 waves 2x2 (each 64x32).
// LDS layout [row][8 k-blocks of 8] with XOR swizzle: slot cb of row r
// holds k-block (cb ^ (r&7)) -> staging stays lane-linear AND coalesced
// (8 lanes of a row cover the same 128B, permuted), ds_read_b128 quarters
// spread over all 32 banks (2-way aliasing = free) instead of 8-way.
// XCD-aware 1D swizzle: xcd = bid&7 owns m-tiles [8*xcd, 8*xcd+8).
// Epilogue: LDS transpose -> coalesced dwordx4 stores.
// MODE 0: +bias;  MODE 1: +bias, softplus cols>=32, skip store col>=544
// ---------------------------------------------------------------------------
template <int MODE>
__global__ __launch_bounds__(256) void gemm_f16(
    const _Float16* __restrict__ A, const _Float16* __restrict__ Bt,
    const float* __restrict__ bias, float* __restrict__ Cmat, int ldc)
{
  const int K = 512;
  int bid = blockIdx.x;
  int xcd = bid & 7;
  int rest = bid >> 3;
  int mloc = rest & 7;
  int nb = rest >> 3;
  int m0 = (xcd * 8 + mloc) * 128;
  int n0 = nb * 64;
  // K-loop staging (24576 B) unioned with epilogue patches (36864 B)
  __shared__ __align__(16) char smem[36864];
  _Float16* As = (_Float16*)smem;         // [128][64]
  _Float16* Bs = As + 128 * 64;           // [64][64]
  int tid = threadIdx.x;
  int wave = tid >> 6, lane = tid & 63;
  int wm = (wave >> 1) * 64;
  int wn = (wave & 1) * 32;
  int lrow = lane & 15;
  int q4 = lane >> 4;
  f32x4 acc[4][2] = {};

  // staging thread-constants: issue j covers rows j*32+(tid>>3)
  int srow = tid >> 3;                            // 0..31
  int scol = ((tid & 7) ^ (srow & 7)) * 8;        // XOR swizzle
  size_t gA = (size_t)(m0 + srow) * K + scol;
  size_t gB = (size_t)(n0 + srow) * K + scol;
  unsigned sdst = (unsigned)(wave * 512);         // + j*2048 elems

  for (int k0 = 0; k0 < K; k0 += 64) {
#pragma unroll
    for (int j = 0; j < 4; ++j)
      __builtin_amdgcn_global_load_lds(
          (const __attribute__((address_space(1))) void*)(A + gA + (size_t)(j * 32) * K + k0),
          (__attribute__((address_space(3))) void*)(&As[j * 2048 + sdst]), 16, 0, 0);
#pragma unroll
    for (int j = 0; j < 2; ++j)
      __builtin_amdgcn_global_load_lds(
          (const __attribute__((address_space(1))) void*)(Bt + gB + (size_t)(j * 32) * K + k0),
          (__attribute__((address_space(3))) void*)(&Bs[j * 2048 + sdst]), 16, 0, 0);
    __syncthreads();
#pragma unroll
    for (int kk = 0; kk < 2; ++kk) {
      half8 af[4], bf[2];
#pragma unroll
      for (int i = 0; i < 4; ++i) {
        int r = wm + i * 16 + lrow;
        int cb = (kk * 4 + q4) ^ (lrow & 7);
        af[i] = *(const half8*)&As[r * 64 + cb * 8];
      }
#pragma unroll
      for (int t = 0; t < 2; ++t) {
        int r = wn + t * 16 + lrow;
        int cb = (kk * 4 + q4) ^ (lrow & 7);
        bf[t] = *(const half8*)&Bs[r * 64 + cb * 8];
      }
#pragma unroll
      for (int i = 0; i < 4; ++i)
#pragma unroll
        for (int t = 0; t < 2; ++t)
          acc[i][t] = __builtin_amdgcn_mfma_f32_16x16x32_f16(af[i], bf[t], acc[i][t], 0, 0, 0);
    }
    __syncthreads();
  }

  // ---- epilogue: bias/softplus on regs, LDS transpose, coalesced store ----
  float* ct = (float*)smem + wave * (64 * 36);   // 64 rows x 32 cols, stride 36
#pragma unroll
  for (int t = 0; t < 2; ++t) {
    int coll = wn + t * 16 + lrow;        // tile-local col 0..63
    float bv = bias[n0 + coll];
    bool sp = (MODE == 1) && (n0 + coll >= 32);
#pragma unroll
    for (int i = 0; i < 4; ++i) {
#pragma unroll
      for (int r = 0; r < 4; ++r) {
        float v = acc[i][t][r] + bv;
        if (sp) v = softplus_f(v);
        ct[(i * 16 + q4 * 4 + r) * 36 + (t * 16 + lrow)] = v;
      }
    }
  }
  __syncthreads();                         // order LDS writes before reads
  int r8 = lane >> 3, c8 = lane & 7;       // 8 rows x (8 lanes * 16B = 128B)
  int colv = n0 + wn + c8 * 4;
  bool do_store = !(MODE == 1 && colv >= 544);   // skip pad columns
#pragma unroll
  for (int pass = 0; pass < 8; ++pass) {
    int rowl = pass * 8 + r8;              // 0..63 local row
    float4 v = *(const float4*)&ct[rowl * 36 + c8 * 4];
    if (do_store)
      *(float4*)&Cmat[(size_t)(m0 + wm + rowl) * ldc + colv] = v;
  }
}

// ---------------------------------------------------------------------------
// fused scan (cooperative, 512 blocks x 256, 2 blocks/CU co-resident):
// phase 1: per (b,chunk,d) local scan (h0=0) + cumulative a-product
// phase 2: segmented cross-chunk scan (identical mapping to old scan_p2)
// phase 3: replay with true initial state; y = C.h + Dskip*x; gelu -> fp16
// grid.sync() between phases replaces 2 kernel launches + reloads.
// ---------------------------------------------------------------------------
template <int PACKED>
__global__ __launch_bounds__(256, 2) void scan_fused(
    const float* __restrict__ Z, const float* __restrict__ Xf,
    const _Float16* __restrict__ Xh, const float* __restrict__ A2,
    float* __restrict__ Ach, float* __restrict__ Uch,
    const float* __restrict__ Dskip, _Float16* __restrict__ Yout)
{
  cg::grid_group grid = cg::this_grid();
  int bid = blockIdx.x;
  int dg = bid & 1, c = (bid >> 1) & (NCHUNK - 1), b = bid >> 7;
  int d = dg * 256 + threadIdx.x;
  int row0 = b * 2048 + c * SCH;
  __shared__ float Bsh[SCH * 16];
  __shared__ float Csh[SCH * 16];
  __shared__ float AsegL[4][64], UsegL[4][64];
  for (int i = threadIdx.x; i < SCH * 16; i += 256) {
    size_t rz = (size_t)(row0 + (i >> 4)) * ZLD;
    Bsh[i] = Z[rz + (i & 15)];
    Csh[i] = Z[rz + 16 + (i & 15)];
  }
  __syncthreads();
  float a2[16];
  const float4* a2v = (const float4*)(A2 + d * 16);
#pragma unroll
  for (int q = 0; q < 4; ++q) {
    float4 f = a2v[q];
    a2[q * 4 + 0] = f.x; a2[q * 4 + 1] = f.y; a2[q * 4 + 2] = f.z; a2[q * 4 + 3] = f.w;
  }

  // ---- phase 1 ----
  {
    float ap[16], u[16];
#pragma unroll
    for (int n = 0; n < 16; ++n) { ap[n] = 1.0f; u[n] = 0.0f; }
    for (int t = 0; t < SCH; ++t) {
      size_t row = row0 + t;
      float dtv = Z[row * ZLD + 32 + d];
      float xv = PACKED ? (float)Xh[row * DD + d] : Xf[row * DD + d];
      float dx = dtv * xv;
#pragma unroll
      for (int n = 0; n < 16; ++n) {
        float e = __builtin_amdgcn_exp2f(dtv * a2[n]);
        u[n] = e * u[n] + dx * Bsh[t * 16 + n];
        ap[n] *= e;
      }
    }
    size_t out = ((size_t)(b * NCHUNK + c) * DD + d) * 16;
#pragma unroll
    for (int n = 0; n < 16; ++n) { Ach[out + n] = ap[n]; Uch[out + n] = u[n]; }
  }
  __threadfence();
  grid.sync();

  // ---- phase 2 (same work split as old standalone scan_p2, 512 blocks) ----
  {
    int b2 = bid >> 7;
    int dn = (bid & 127) * 64 + (threadIdx.x & 63);
    int seg = threadIdx.x >> 6;
    size_t base = (size_t)b2 * NCHUNK * 8192 + dn;
    float a_r[16], u_r[16];
#pragma unroll
    for (int i = 0; i < 16; ++i) {
      size_t idx = base + (size_t)(seg * 16 + i) * 8192;
      a_r[i] = Ach[idx];
      u_r[i] = Uch[idx];
    }
    float Ap = 1.0f, hA = 0.0f;
#pragma unroll
    for (int i = 0; i < 16; ++i) { hA = a_r[i] * hA + u_r[i]; Ap *= a_r[i]; }
    AsegL[seg][threadIdx.x & 63] = Ap;
    UsegL[seg][threadIdx.x & 63] = hA;
    __syncthreads();
    float h = 0.0f;
    for (int s = 0; s < seg; ++s)
      h = AsegL[s][threadIdx.x & 63] * h + UsegL[s][threadIdx.x & 63];
#pragma unroll
    for (int i = 0; i < 16; ++i) {
      size_t idx = base + (size_t)(seg * 16 + i) * 8192;
      Uch[idx] = h;                          // Hinit for chunk seg*16+i
      h = a_r[i] * h + u_r[i];
    }
  }
  __threadfence();
  grid.sync();

  // ---- phase 3 ----
  {
    float h[16];
    size_t hidx = ((size_t)(b * NCHUNK + c) * DD + d) * 16;
#pragma unroll
    for (int n = 0; n < 16; ++n) h[n] = Uch[hidx + n];
    float dsk = Dskip[d];
    for (int t = 0; t < SCH; ++t) {
      size_t row = row0 + t;
      float dtv = Z[row * ZLD + 32 + d];
      float xv = PACKED ? (float)Xh[row * DD + d] : Xf[row * DD + d];
      float dx = dtv * xv;
      float acc = 0.0f;
#pragma unroll
      for (int n = 0; n < 16; ++n) {
        float e = __builtin_amdgcn_exp2f(dtv * a2[n]);
        h[n] = e * h[n] + dx * Bsh[t * 16 + n];
        acc += Csh[t * 16 + n] * h[n];
      }
      float y = acc + dsk * xv;
      Yout[row * DD + d] = (_Float16)gelu_erf(y);
    }
  }
}

// ---------------------------------------------------------------------------
// LayerNorm + residual: H = Hin + LN(Y2)*g + b -> fp16.
// one wave per row, 8 elems/lane, fully vectorized loads/stores.
// ---------------------------------------------------------------------------
template <int PACKED>
__global__ __launch_bounds__(256) void ln_residual(
    const float* __restrict__ Y2, const float* Xf,
    const float* __restrict__ gam, const float* __restrict__ bet,
    _Float16* Hh)
{
  int wave = threadIdx.x >> 6, lane = threadIdx.x & 63;
  size_t row = (size_t)blockIdx.x * 4 + wave;
  size_t gbase = row * DD + lane * 8;
  const float4* yr = (const float4*)(Y2 + gbase);
  float4 y0 = yr[0], y1 = yr[1];
  float v[8] = {y0.x, y0.y, y0.z, y0.w, y1.x, y1.y, y1.z, y1.w};
  float s = 0.0f, sq = 0.0f;
#pragma unroll
  for (int j = 0; j < 8; ++j) { s += v[j]; sq += v[j] * v[j]; }
#pragma unroll
  for (int off = 32; off; off >>= 1) {
    s += __shfl_xor(s, off, 64);
    sq += __shfl_xor(sq, off, 64);
  }
  float mu = s * (1.0f / 512.0f);
  float var = sq * (1.0f / 512.0f) - mu * mu;
  float rstd = rsqrtf(var + 1e-5f);

  float hin[8];
  if (PACKED) {
    half8 hh = *(const half8*)(Hh + gbase);
#pragma unroll
    for (int j = 0; j < 8; ++j) hin[j] = (float)hh[j];
  } else {
    const float4* xr = (const float4*)(Xf + gbase);
    float4 x0 = xr[0], x1 = xr[1];
    hin[0]=x0.x; hin[1]=x0.y; hin[2]=x0.z; hin[3]=x0.w;
    hin[4]=x1.x; hin[5]=x1.y; hin[6]=x1.z; hin[7]=x1.w;
  }
  const float4* g4 = (const float4*)(gam + lane * 8);
  const float4* b4 = (const float4*)(bet + lane * 8);
  float4 g0 = g4[0], g1 = g4[1], bb0 = b4[0], bb1 = b4[1];
  float gv[8] = {g0.x,g0.y,g0.z,g0.w,g1.x,g1.y,g1.z,g1.w};
  float bv[8] = {bb0.x,bb0.y,bb0.z,bb0.w,bb1.x,bb1.y,bb1.z,bb1.w};
  half8 sh;
#pragma unroll
  for (int j = 0; j < 8; ++j) {
    float o = (v[j] - mu) * rstd * gv[j] + bv[j] + hin[j];
    sh[j] = (_Float16)o;
  }
  *(half8*)(Hh + gbase) = sh;
}

// ---------------------------------------------------------------------------
extern "C" void kernel_launch(void* const* d_in, const int* in_sizes, int n_in,
                              void* d_out, int out_size, void* d_ws, size_t ws_size,
                              hipStream_t stream) {
  const float* x      = (const float*)d_in[0];
  const float* A_log  = (const float*)d_in[1];
  const float* W_B    = (const float*)d_in[2];
  const float* b_B    = (const float*)d_in[3];
  const float* W_C    = (const float*)d_in[4];
  const float* b_C    = (const float*)d_in[5];
  const float* W_dt   = (const float*)d_in[6];
  const float* b_dt   = (const float*)d_in[7];
  const float* D_skip = (const float*)d_in[8];
  const float* W_mix  = (const float*)d_in[9];
  const float* b_mix  = (const float*)d_in[10];
  const float* ln_g   = (const float*)d_in[11];
  const float* ln_b   = (const float*)d_in[12];
  const float* W_dec  = (const float*)d_in[13];
  const float* b_dec  = (const float*)d_in[14];

  char* ws = (char*)d_ws;
  size_t off = 0;
  // region1 (8MB): x16 -> per layer Ach (x16 dead after gemm cat l=0)
  _Float16* x16 = (_Float16*)(ws + off);
  float*    Ach = (float*)(ws + off);     off += 8388608;
  _Float16* y16 = (_Float16*)(ws + off);  off += 8388608;  // p3 out (fp16)
  _Float16* h16 = (_Float16*)(ws + off);  off += 8388608;  // residual stream
  // region3 (20MB): Z [8192][640] fp32; y2 (16MB) aliases (Z dead after p3)
  float* Z    = (float*)(ws + off);
  float* y2   = (float*)(ws + off); off += 20971520;
  float* Uch  = (float*)(ws + off); off += 8388608; // chunk partials / Hinit
  _Float16* Wc16 = (_Float16*)(ws + off); off += 1310720; // [2][640][512]
  _Float16* Wm16 = (_Float16*)(ws + off); off += 1048576;
  _Float16* Wd16 = (_Float16*)(ws + off); off += 524288;
  float* bcat = (float*)(ws + off); off += 5120;    // [2][640]
  float* A2w  = (float*)(ws + off); off += 65536;   // [2][512][16]

  prep_kernel<<<(PREP_TOT + 255) / 256, 256, 0, stream>>>(
      x, A_log, W_B, b_B, W_C, b_C, W_dt, b_dt, W_mix, W_dec,
      x16, Wc16, Wm16, Wd16, bcat, A2w);

  for (int l = 0; l < 2; ++l) {
    const _Float16* Ain = (l == 0) ? x16 : h16;
    gemm_f16<1><<<576, 256, 0, stream>>>(
        Ain, Wc16 + l * 640 * 512, bcat + l * 640, Z, ZLD);

    {
      const float* Zc = Z;
      const float* Xfc = (l == 0) ? x : nullptr;
      const _Float16* Xhc = (l == 0) ? nullptr : h16;
      const float* A2c = A2w + l * 8192;
      float* Achc = Ach; float* Uchc = Uch;
      const float* Dc = D_skip + l * 512;
      _Float16* Yc = y16;
      void* args[] = {&Zc, &Xfc, &Xhc, &A2c, &Achc, &Uchc, &Dc, &Yc};
      if (l == 0) {
        void (*fn)(const float*, const float*, const _Float16*, const float*,
                   float*, float*, const float*, _Float16*) = scan_fused<0>;
        hipLaunchCooperativeKernel((void*)fn, dim3(512), dim3(256), args, 0, stream);
      } else {
        void (*fn)(const float*, const float*, const _Float16*, const float*,
                   float*, float*, const float*, _Float16*) = scan_fused<1>;
        hipLaunchCooperativeKernel((void*)fn, dim3(512), dim3(256), args, 0, stream);
      }
    }

    gemm_f16<0><<<512, 256, 0, stream>>>(
        y16, Wm16 + l * 512 * 512, b_mix + l * 512, y2, DD);
    if (l == 0)
      ln_residual<0><<<2048, 256, 0, stream>>>(y2, x, ln_g + l * 512,
                                               ln_b + l * 512, h16);
    else
      ln_residual<1><<<2048, 256, 0, stream>>>(y2, nullptr, ln_g + l * 512,
                                               ln_b + l * 512, h16);
  }
  gemm_f16<0><<<512, 256, 0, stream>>>(
      h16, Wd16, b_dec, (float*)d_out, DD);
}

// Round 9
// 281.705 us; speedup vs baseline: 2.6960x; 2.6960x over previous
//
#include <hip/hip_runtime.h>
#include <math.h>

typedef unsigned short u16;
typedef unsigned int u32;
typedef __attribute__((ext_vector_type(8))) _Float16 half8;
typedef __attribute__((ext_vector_type(4))) float f32x4;

#define BL 8192          // B*L
#define DD 512           // d_model
#define NN 16            // state size
#define NCHUNK 64        // chunks per sequence
#define SCH 32           // chunk length (NCHUNK*SCH = L = 2048)
#define ZLD 640          // padded width of Z = [Bm(16)|Cm(16)|dt(512)|pad(96)]

__device__ __forceinline__ float softplus_f(float z) {
  float w = __builtin_amdgcn_exp2f(-1.4426950408889634f * fabsf(z));
  return fmaxf(z, 0.0f) + 0.69314718055994531f * __builtin_amdgcn_logf(1.0f + w);
}

__device__ __forceinline__ float gelu_erf(float y) {
  // exact-erf gelu via Abramowitz-Stegun 7.1.26 (max err ~1.5e-7)
  float ax = fabsf(y) * 0.70710678118654752f;
  float t  = __builtin_amdgcn_rcpf(1.0f + 0.3275911f * ax);
  float e  = __builtin_amdgcn_exp2f(-1.4426950408889634f * ax * ax);
  float p  = ((((1.061405429f * t - 1.453152027f) * t + 1.421413741f) * t
               - 0.284496736f) * t + 0.254829592f) * t;
  float er = copysignf(1.0f - p * e, y);
  return 0.5f * y * (1.0f + er);
}

// ---------------------------------------------------------------------------
// prep: fp16 copies of x and (transposed) weights, bias concat, A2
// ---------------------------------------------------------------------------
#define PREP_TOT (4194304 + 655360 + 524288 + 262144 + 1280 + 16384)
__global__ __launch_bounds__(256) void prep_kernel(
    const float* __restrict__ x, const float* __restrict__ A_log,
    const float* __restrict__ W_B, const float* __restrict__ b_B,
    const float* __restrict__ W_C, const float* __restrict__ b_C,
    const float* __restrict__ W_dt, const float* __restrict__ b_dt,
    const float* __restrict__ W_mix, const float* __restrict__ W_dec,
    _Float16* __restrict__ x16, _Float16* __restrict__ Wc16,
    _Float16* __restrict__ Wm16, _Float16* __restrict__ Wd16,
    float* __restrict__ bcat, float* __restrict__ A2)
{
  int i = blockIdx.x * 256 + threadIdx.x;
  if (i >= PREP_TOT) return;
  if (i < 4194304) { x16[i] = (_Float16)x[i]; return; }
  i -= 4194304;
  if (i < 655360) {                       // WcatT[l][n(640)][k(512)]
    int l = i / 327680, r = i % 327680, n = r >> 9, k = r & 511;
    float v = 0.0f;
    if (n < 16)       v = W_B[l * 8192 + k * 16 + n];
    else if (n < 32)  v = W_C[l * 8192 + k * 16 + (n - 16)];
    else if (n < 544) v = W_dt[l * 262144 + k * 512 + (n - 32)];
    Wc16[i] = (_Float16)v;
    return;
  }
  i -= 655360;
  if (i < 524288) {                       // WmixT[l][n][k]
    int l = i / 262144, r = i % 262144, n = r >> 9, k = r & 511;
    Wm16[i] = (_Float16)W_mix[l * 262144 + k * 512 + n];
    return;
  }
  i -= 524288;
  if (i < 262144) {                       // WdecT[n][k]
    int n = i >> 9, k = i & 511;
    Wd16[i] = (_Float16)W_dec[k * 512 + n];
    return;
  }
  i -= 262144;
  if (i < 1280) {                         // bcat[l][640]
    int l = i / 640, n = i % 640;
    float v = 0.0f;
    if (n < 16)       v = b_B[l * 16 + n];
    else if (n < 32)  v = b_C[l * 16 + (n - 16)];
    else if (n < 544) v = b_dt[l * 512 + (n - 32)];
    bcat[i] = v;
    return;
  }
  i -= 1280;
  // A2[l][d][n] = -exp(A_log)*log2(e)  (so a = exp2(dt*A2))
  A2[i] = -expf(A_log[i]) * 1.4426950408889634f;
}

// ---------------------------------------------------------------------------
// fp16 MFMA GEMM: C = A * Bt^T + bias. tile 128(M) x 64(N), BK=64 (8
// barriers), 256 threads = 4 waves 2x2 (each 64x32).
// LDS layout [row][8 k-blocks of 8] with XOR swizzle: slot cb of row r
// holds k-block (cb ^ (r&7)) -> staging lane-linear AND coalesced,
// ds_read_b128 quarters spread over all 32 banks (2-way = free).
// XCD-aware 1D swizzle: xcd = bid&7 owns m-tiles [8*xcd, 8*xcd+8).
// Epilogue: LDS transpose -> coalesced dwordx4 stores.
// MODE 0: +bias;  MODE 1: +bias, softplus cols>=32, skip store col>=544
// ---------------------------------------------------------------------------
template <int MODE>
__global__ __launch_bounds__(256) void gemm_f16(
    const _Float16* __restrict__ A, const _Float16* __restrict__ Bt,
    const float* __restrict__ bias, float* __restrict__ Cmat, int ldc)
{
  const int K = 512;
  int bid = blockIdx.x;
  int xcd = bid & 7;
  int rest = bid >> 3;
  int mloc = rest & 7;
  int nb = rest >> 3;
  int m0 = (xcd * 8 + mloc) * 128;
  int n0 = nb * 64;
  // K-loop staging (24576 B) unioned with epilogue patches (36864 B)
  __shared__ __align__(16) char smem[36864];
  _Float16* As = (_Float16*)smem;         // [128][64]
  _Float16* Bs = As + 128 * 64;           // [64][64]
  int tid = threadIdx.x;
  int wave = tid >> 6, lane = tid & 63;
  int wm = (wave >> 1) * 64;
  int wn = (wave & 1) * 32;
  int lrow = lane & 15;
  int q4 = lane >> 4;
  f32x4 acc[4][2] = {};

  // staging thread-constants: issue j covers rows j*32+(tid>>3)
  int srow = tid >> 3;                            // 0..31
  int scol = ((tid & 7) ^ (srow & 7)) * 8;        // XOR swizzle
  size_t gA = (size_t)(m0 + srow) * K + scol;
  size_t gB = (size_t)(n0 + srow) * K + scol;
  unsigned sdst = (unsigned)(wave * 512);         // + j*2048 elems

  for (int k0 = 0; k0 < K; k0 += 64) {
#pragma unroll
    for (int j = 0; j < 4; ++j)
      __builtin_amdgcn_global_load_lds(
          (const __attribute__((address_space(1))) void*)(A + gA + (size_t)(j * 32) * K + k0),
          (__attribute__((address_space(3))) void*)(&As[j * 2048 + sdst]), 16, 0, 0);
#pragma unroll
    for (int j = 0; j < 2; ++j)
      __builtin_amdgcn_global_load_lds(
          (const __attribute__((address_space(1))) void*)(Bt + gB + (size_t)(j * 32) * K + k0),
          (__attribute__((address_space(3))) void*)(&Bs[j * 2048 + sdst]), 16, 0, 0);
    __syncthreads();
#pragma unroll
    for (int kk = 0; kk < 2; ++kk) {
      half8 af[4], bf[2];
#pragma unroll
      for (int i = 0; i < 4; ++i) {
        int r = wm + i * 16 + lrow;
        int cb = (kk * 4 + q4) ^ (lrow & 7);
        af[i] = *(const half8*)&As[r * 64 + cb * 8];
      }
#pragma unroll
      for (int t = 0; t < 2; ++t) {
        int r = wn + t * 16 + lrow;
        int cb = (kk * 4 + q4) ^ (lrow & 7);
        bf[t] = *(const half8*)&Bs[r * 64 + cb * 8];
      }
#pragma unroll
      for (int i = 0; i < 4; ++i)
#pragma unroll
        for (int t = 0; t < 2; ++t)
          acc[i][t] = __builtin_amdgcn_mfma_f32_16x16x32_f16(af[i], bf[t], acc[i][t], 0, 0, 0);
    }
    __syncthreads();
  }

  // ---- epilogue: bias/softplus on regs, LDS transpose, coalesced store ----
  float* ct = (float*)smem + wave * (64 * 36);   // 64 rows x 32 cols, stride 36
#pragma unroll
  for (int t = 0; t < 2; ++t) {
    int coll = wn + t * 16 + lrow;        // tile-local col 0..63
    float bv = bias[n0 + coll];
    bool sp = (MODE == 1) && (n0 + coll >= 32);
#pragma unroll
    for (int i = 0; i < 4; ++i) {
#pragma unroll
      for (int r = 0; r < 4; ++r) {
        float v = acc[i][t][r] + bv;
        if (sp) v = softplus_f(v);
        ct[(i * 16 + q4 * 4 + r) * 36 + (t * 16 + lrow)] = v;
      }
    }
  }
  __syncthreads();                         // order LDS writes before reads
  int r8 = lane >> 3, c8 = lane & 7;       // 8 rows x (8 lanes * 16B = 128B)
  int colv = n0 + wn + c8 * 4;
  bool do_store = !(MODE == 1 && colv >= 544);   // skip pad columns
#pragma unroll
  for (int pass = 0; pass < 8; ++pass) {
    int rowl = pass * 8 + r8;              // 0..63 local row
    float4 v = *(const float4*)&ct[rowl * 36 + c8 * 4];
    if (do_store)
      *(float4*)&Cmat[(size_t)(m0 + wm + rowl) * ldc + colv] = v;
  }
}

// ---------------------------------------------------------------------------
// scan phase 1: per (b, chunk, d) cumulative a-product + local scan (h0=0).
// grid = B*NCHUNK*2 blocks of 256 threads. X: fp32 (PACKED=0) or fp16 (1).
// ---------------------------------------------------------------------------
template <int PACKED>
__global__ __launch_bounds__(256) void scan_p1(
    const float* __restrict__ Z, const float* __restrict__ Xf,
    const _Float16* __restrict__ Xh, const float* __restrict__ A2,
    float* __restrict__ Ach, float* __restrict__ Uch)
{
  int bid = blockIdx.x;
  int dg = bid & 1, c = (bid >> 1) & (NCHUNK - 1), b = bid >> 7;
  int d = dg * 256 + threadIdx.x;
  int row0 = b * 2048 + c * SCH;
  __shared__ float Bsh[SCH * 16];
  for (int i = threadIdx.x; i < SCH * 16; i += 256)
    Bsh[i] = Z[(size_t)(row0 + (i >> 4)) * ZLD + (i & 15)];
  __syncthreads();
  float a2[16];
  const float4* a2v = (const float4*)(A2 + d * 16);
#pragma unroll
  for (int q = 0; q < 4; ++q) {
    float4 f = a2v[q];
    a2[q * 4 + 0] = f.x; a2[q * 4 + 1] = f.y; a2[q * 4 + 2] = f.z; a2[q * 4 + 3] = f.w;
  }
  float ap[16], u[16];
#pragma unroll
  for (int n = 0; n < 16; ++n) { ap[n] = 1.0f; u[n] = 0.0f; }
  for (int t = 0; t < SCH; ++t) {
    size_t row = row0 + t;
    float dtv = Z[row * ZLD + 32 + d];
    float xv = PACKED ? (float)Xh[row * DD + d] : Xf[row * DD + d];
    float dx = dtv * xv;
#pragma unroll
    for (int n = 0; n < 16; ++n) {
      float e = __builtin_amdgcn_exp2f(dtv * a2[n]);
      u[n] = e * u[n] + dx * Bsh[t * 16 + n];
      ap[n] *= e;
    }
  }
  size_t out = ((size_t)(b * NCHUNK + c) * DD + d) * 16;
#pragma unroll
  for (int n = 0; n < 16; ++n) { Ach[out + n] = ap[n]; Uch[out + n] = u[n]; }
}

// ---------------------------------------------------------------------------
// scan phase 2 (segmented): 4 threads per (b,dn), each scans 16 chunks in
// registers; LDS carry exchange; rewrite Uch as Hinit. 512 blocks x 256.
// ---------------------------------------------------------------------------
__global__ __launch_bounds__(256) void scan_p2(
    const float* __restrict__ Ach, float* __restrict__ Uch)
{
  int blk = blockIdx.x;
  int b = blk >> 7;
  int dn = (blk & 127) * 64 + (threadIdx.x & 63);
  int seg = threadIdx.x >> 6;
  size_t base = (size_t)b * NCHUNK * 8192 + dn;
  float a_r[16], u_r[16];
#pragma unroll
  for (int i = 0; i < 16; ++i) {
    size_t idx = base + (size_t)(seg * 16 + i) * 8192;
    a_r[i] = Ach[idx];
    u_r[i] = Uch[idx];
  }
  float Ap = 1.0f, hA = 0.0f;
#pragma unroll
  for (int i = 0; i < 16; ++i) { hA = a_r[i] * hA + u_r[i]; Ap *= a_r[i]; }
  __shared__ float AsegL[4][64], UsegL[4][64];
  AsegL[seg][threadIdx.x & 63] = Ap;
  UsegL[seg][threadIdx.x & 63] = hA;
  __syncthreads();
  float h = 0.0f;
  for (int s = 0; s < seg; ++s)
    h = AsegL[s][threadIdx.x & 63] * h + UsegL[s][threadIdx.x & 63];
#pragma unroll
  for (int i = 0; i < 16; ++i) {
    size_t idx = base + (size_t)(seg * 16 + i) * 8192;
    Uch[idx] = h;
    h = a_r[i] * h + u_r[i];
  }
}

// ---------------------------------------------------------------------------
// scan phase 3: replay chunk with true initial state; y = C.h + Dskip*x;
// gelu(exact erf); write fp16
// ---------------------------------------------------------------------------
template <int PACKED>
__global__ __launch_bounds__(256) void scan_p3(
    const float* __restrict__ Z, const float* __restrict__ Xf,
    const _Float16* __restrict__ Xh, const float* __restrict__ A2,
    const float* __restrict__ Hinit, const float* __restrict__ Dskip,
    _Float16* __restrict__ Yout)
{
  int bid = blockIdx.x;
  int dg = bid & 1, c = (bid >> 1) & (NCHUNK - 1), b = bid >> 7;
  int d = dg * 256 + threadIdx.x;
  int row0 = b * 2048 + c * SCH;
  __shared__ float Bsh[SCH * 16];
  __shared__ float Csh[SCH * 16];
  for (int i = threadIdx.x; i < SCH * 16; i += 256) {
    size_t rz = (size_t)(row0 + (i >> 4)) * ZLD;
    Bsh[i] = Z[rz + (i & 15)];
    Csh[i] = Z[rz + 16 + (i & 15)];
  }
  __syncthreads();
  float a2[16];
  const float4* a2v = (const float4*)(A2 + d * 16);
#pragma unroll
  for (int q = 0; q < 4; ++q) {
    float4 f = a2v[q];
    a2[q * 4 + 0] = f.x; a2[q * 4 + 1] = f.y; a2[q * 4 + 2] = f.z; a2[q * 4 + 3] = f.w;
  }
  float h[16];
  size_t hidx = ((size_t)(b * NCHUNK + c) * DD + d) * 16;
#pragma unroll
  for (int n = 0; n < 16; ++n) h[n] = Hinit[hidx + n];
  float dsk = Dskip[d];
  for (int t = 0; t < SCH; ++t) {
    size_t row = row0 + t;
    float dtv = Z[row * ZLD + 32 + d];
    float xv = PACKED ? (float)Xh[row * DD + d] : Xf[row * DD + d];
    float dx = dtv * xv;
    float acc = 0.0f;
#pragma unroll
    for (int n = 0; n < 16; ++n) {
      float e = __builtin_amdgcn_exp2f(dtv * a2[n]);
      h[n] = e * h[n] + dx * Bsh[t * 16 + n];
      acc += Csh[t * 16 + n] * h[n];
    }
    float y = acc + dsk * xv;
    Yout[row * DD + d] = (_Float16)gelu_erf(y);
  }
}

// ---------------------------------------------------------------------------
// LayerNorm + residual: H = Hin + LN(Y2)*g + b -> fp16.
// one wave per row, 8 elems/lane, fully vectorized loads/stores.
// ---------------------------------------------------------------------------
template <int PACKED>
__global__ __launch_bounds__(256) void ln_residual(
    const float* __restrict__ Y2, const float* Xf,
    const float* __restrict__ gam, const float* __restrict__ bet,
    _Float16* Hh)
{
  int wave = threadIdx.x >> 6, lane = threadIdx.x & 63;
  size_t row = (size_t)blockIdx.x * 4 + wave;
  size_t gbase = row * DD + lane * 8;
  const float4* yr = (const float4*)(Y2 + gbase);
  float4 y0 = yr[0], y1 = yr[1];
  float v[8] = {y0.x, y0.y, y0.z, y0.w, y1.x, y1.y, y1.z, y1.w};
  float s = 0.0f, sq = 0.0f;
#pragma unroll
  for (int j = 0; j < 8; ++j) { s += v[j]; sq += v[j] * v[j]; }
#pragma unroll
  for (int off = 32; off; off >>= 1) {
    s += __shfl_xor(s, off, 64);
    sq += __shfl_xor(sq, off, 64);
  }
  float mu = s * (1.0f / 512.0f);
  float var = sq * (1.0f / 512.0f) - mu * mu;
  float rstd = rsqrtf(var + 1e-5f);

  float hin[8];
  if (PACKED) {
    half8 hh = *(const half8*)(Hh + gbase);
#pragma unroll
    for (int j = 0; j < 8; ++j) hin[j] = (float)hh[j];
  } else {
    const float4* xr = (const float4*)(Xf + gbase);
    float4 x0 = xr[0], x1 = xr[1];
    hin[0]=x0.x; hin[1]=x0.y; hin[2]=x0.z; hin[3]=x0.w;
    hin[4]=x1.x; hin[5]=x1.y; hin[6]=x1.z; hin[7]=x1.w;
  }
  const float4* g4 = (const float4*)(gam + lane * 8);
  const float4* b4 = (const float4*)(bet + lane * 8);
  float4 g0 = g4[0], g1 = g4[1], bb0 = b4[0], bb1 = b4[1];
  float gv[8] = {g0.x,g0.y,g0.z,g0.w,g1.x,g1.y,g1.z,g1.w};
  float bv[8] = {bb0.x,bb0.y,bb0.z,bb0.w,bb1.x,bb1.y,bb1.z,bb1.w};
  half8 sh;
#pragma unroll
  for (int j = 0; j < 8; ++j) {
    float o = (v[j] - mu) * rstd * gv[j] + bv[j] + hin[j];
    sh[j] = (_Float16)o;
  }
  *(half8*)(Hh + gbase) = sh;
}

// ---------------------------------------------------------------------------
extern "C" void kernel_launch(void* const* d_in, const int* in_sizes, int n_in,
                              void* d_out, int out_size, void* d_ws, size_t ws_size,
                              hipStream_t stream) {
  const float* x      = (const float*)d_in[0];
  const float* A_log  = (const float*)d_in[1];
  const float* W_B    = (const float*)d_in[2];
  const float* b_B    = (const float*)d_in[3];
  const float* W_C    = (const float*)d_in[4];
  const float* b_C    = (const float*)d_in[5];
  const float* W_dt   = (const float*)d_in[6];
  const float* b_dt   = (const float*)d_in[7];
  const float* D_skip = (const float*)d_in[8];
  const float* W_mix  = (const float*)d_in[9];
  const float* b_mix  = (const float*)d_in[10];
  const float* ln_g   = (const float*)d_in[11];
  const float* ln_b   = (const float*)d_in[12];
  const float* W_dec  = (const float*)d_in[13];
  const float* b_dec  = (const float*)d_in[14];

  char* ws = (char*)d_ws;
  size_t off = 0;
  // region1 (8MB): x16 -> per layer Ach (x16 dead after gemm cat l=0)
  _Float16* x16 = (_Float16*)(ws + off);
  float*    Ach = (float*)(ws + off);     off += 8388608;
  _Float16* y16 = (_Float16*)(ws + off);  off += 8388608;  // p3 out (fp16)
  _Float16* h16 = (_Float16*)(ws + off);  off += 8388608;  // residual stream
  // region3 (20MB): Z [8192][640] fp32; y2 (16MB) aliases (Z dead after p3)
  float* Z    = (float*)(ws + off);
  float* y2   = (float*)(ws + off); off += 20971520;
  float* Uch  = (float*)(ws + off); off += 8388608; // chunk partials / Hinit
  _Float16* Wc16 = (_Float16*)(ws + off); off += 1310720; // [2][640][512]
  _Float16* Wm16 = (_Float16*)(ws + off); off += 1048576;
  _Float16* Wd16 = (_Float16*)(ws + off); off += 524288;
  float* bcat = (float*)(ws + off); off += 5120;    // [2][640]
  float* A2w  = (float*)(ws + off); off += 65536;   // [2][512][16]

  prep_kernel<<<(PREP_TOT + 255) / 256, 256, 0, stream>>>(
      x, A_log, W_B, b_B, W_C, b_C, W_dt, b_dt, W_mix, W_dec,
      x16, Wc16, Wm16, Wd16, bcat, A2w);

  for (int l = 0; l < 2; ++l) {
    const _Float16* Ain = (l == 0) ? x16 : h16;
    gemm_f16<1><<<576, 256, 0, stream>>>(
        Ain, Wc16 + l * 640 * 512, bcat + l * 640, Z, ZLD);
    if (l == 0) {
      scan_p1<0><<<512, 256, 0, stream>>>(Z, x, nullptr,
                                          A2w + l * 8192, Ach, Uch);
      scan_p2<<<512, 256, 0, stream>>>(Ach, Uch);
      scan_p3<0><<<512, 256, 0, stream>>>(Z, x, nullptr, A2w + l * 8192,
                                          Uch, D_skip + l * 512, y16);
    } else {
      scan_p1<1><<<512, 256, 0, stream>>>(Z, nullptr, h16,
                                          A2w + l * 8192, Ach, Uch);
      scan_p2<<<512, 256, 0, stream>>>(Ach, Uch);
      scan_p3<1><<<512, 256, 0, stream>>>(Z, nullptr, h16, A2w + l * 8192,
                                          Uch, D_skip + l * 512, y16);
    }
    gemm_f16<0><<<512, 256, 0, stream>>>(
        y16, Wm16 + l * 512 * 512, b_mix + l * 512, y2, DD);
    if (l == 0)
      ln_residual<0><<<2048, 256, 0, stream>>>(y2, x, ln_g + l * 512,
                                               ln_b + l * 512, h16);
    else
      ln_residual<1><<<2048, 256, 0, stream>>>(y2, nullptr, ln_g + l * 512,
                                               ln_b + l * 512, h16);
  }
  gemm_f16<0><<<512, 256, 0, stream>>>(
      h16, Wd16, b_dec, (float*)d_out, DD);
}